// Round 9
// baseline (126.569 us; speedup 1.0000x reference)
//
#include <hip/hip_runtime.h>
#include <hip/hip_bf16.h>
#include <math.h>

#define DEVI __device__ __forceinline__

typedef __attribute__((ext_vector_type(4))) float f32x4;
typedef __attribute__((ext_vector_type(8))) short bf16x8;

DEVI unsigned short f2bf(float f) {
  union { float f; unsigned int u; } v; v.f = f;
  return (unsigned short)((v.u + 0x7FFFu + ((v.u >> 16) & 1u)) >> 16);
}
DEVI float bf2f(unsigned short s) {
  union { unsigned int u; float f; } v; v.u = ((unsigned int)s) << 16; return v.f;
}
DEVI bf16x8 pack8(f32x4 a, f32x4 b) {
  bf16x8 r;
  r[0] = (short)f2bf(a[0]); r[1] = (short)f2bf(a[1]);
  r[2] = (short)f2bf(a[2]); r[3] = (short)f2bf(a[3]);
  r[4] = (short)f2bf(b[0]); r[5] = (short)f2bf(b[1]);
  r[6] = (short)f2bf(b[2]); r[7] = (short)f2bf(b[3]);
  return r;
}
DEVI void gload16(const unsigned short* g, unsigned short* l) {
  __builtin_amdgcn_global_load_lds(
      (const __attribute__((address_space(1))) unsigned int*)g,
      (__attribute__((address_space(3))) unsigned int*)l, 16, 0, 0);
}
// raw workgroup barrier WITHOUT the implicit vmcnt(0) drain of __syncthreads
#define SBAR() do { asm volatile("" ::: "memory"); \
                    __builtin_amdgcn_s_barrier();  \
                    asm volatile("" ::: "memory"); } while (0)

// ==== prep: weights f32[K][512] -> bf16 [512][K] swz ; f32[M][K] -> bf16 [M][K] swz
// swizzle: within each 64-elem k-group, kblock kb of row n stored at ((kb+n)&7).
struct PrepJobs {
  const float* src[9];
  unsigned short* dst[9];
  int K[9];
  int base[9];
  int type[9];   // 0 = weight transpose (64x64 tiles), 1 = row-major convert
};

__global__ __launch_bounds__(256) void prep(PrepJobs J) {
  __shared__ float t[64][65];   // 16.6 KB
  int tile = blockIdx.x;
  int job = 0;
  while (job < 8 && tile >= J.base[job + 1]) ++job;
  int tl = tile - J.base[job];
  int K = J.K[job];
  if (J.type[job] == 0) {
    int tn = tl & 7, tk = tl >> 3;   // 512/64 = 8 n-tiles
    int x = threadIdx.x & 63, y = threadIdx.x >> 6;
    const float* s = J.src[job];
    int k0 = tk * 64, n0 = tn * 64;
#pragma unroll
    for (int yy = y; yy < 64; yy += 4)
      t[yy][x] = s[(size_t)(k0 + yy) * 512 + n0 + x];
    __syncthreads();
    unsigned short* d = J.dst[job];
    int kb = (x >> 3) & 7, ko = x & 7;   // k = k0 + x, k0 % 64 == 0
#pragma unroll
    for (int yy = y; yy < 64; yy += 4) {
      int n = n0 + yy;
      int kswz = k0 + (((kb + n) & 7) << 3) + ko;
      d[(size_t)n * K + kswz] = f2bf(t[x][yy]);
    }
  } else {
    int nk = K >> 6;
    int rt = tl / nk;
    int r0 = rt * 64, k0 = (tl - rt * nk) * 64;
    int r = threadIdx.x >> 2, kq = threadIdx.x & 3;
    int row = r0 + r;
    const float* s = J.src[job] + (size_t)row * K + k0 + kq * 16;
    f32x4 a0 = *(const f32x4*)s;
    f32x4 a1 = *(const f32x4*)(s + 4);
    f32x4 a2 = *(const f32x4*)(s + 8);
    f32x4 a3 = *(const f32x4*)(s + 12);
    unsigned short* d = J.dst[job] + (size_t)row * K + k0;
    int kb0 = kq * 2;
    *(bf16x8*)(d + ((kb0 + row) & 7) * 8) = pack8(a0, a1);
    *(bf16x8*)(d + ((kb0 + 1 + row) & 7) * 8) = pack8(a2, a3);
  }
}

// ==== MFMA GEMM, counted-vmcnt double-buffer, templated tile ===============
// BM = MI*32, BN = NI*32, BK = 64; 4 waves (2m x 2n), wave tile (MI*16)x(NI*16).
// C[M][N] = concat(A0|A1|A2) @ B (+ bias). A/B bf16 pre-swizzled; staging is
// pure global_load_lds DMA; s_waitcnt vmcnt(MI+NI) keeps next tile in flight.
// mode 0: bf16 row-major out. mode 1: f32 row-major out. mode 2: bf16 out
// with per-row k-group swizzle (so C can be consumed as a B operand later).
struct GJob {
  const unsigned short* A0; const unsigned short* A1; const unsigned short* A2;
  const unsigned short* Bt;
  const float* bias;        // may be nullptr
  unsigned short* Cb;
  float* Cf;
  int Astride, Bstride, Cstride, nTilesN, nt, lgSteps, mode, tileBase;
};
struct GBatch { GJob j[7]; int njobs; int swz; };

template <int MI, int NI>
__global__ __launch_bounds__(256) void gemm_pipe(GBatch batch) {
  constexpr int BM = MI * 32, BN = NI * 32;
  int gt = blockIdx.x;
  if (batch.swz) {                         // XCD swizzle only for homogeneous grids
    int cpx = gridDim.x >> 3;
    gt = (blockIdx.x & 7) * cpx + (blockIdx.x >> 3);
  }
  int job = 0;
#pragma unroll
  for (int i = 1; i < 7; ++i)
    if (i < batch.njobs && gt >= batch.j[i].tileBase) job = i;
  GJob J = batch.j[job];
  int tl = gt - J.tileBase;
  int bm = (tl / J.nTilesN) * BM, bn = (tl % J.nTilesN) * BN;

  __shared__ __align__(16) unsigned short La[2][BM * 64];
  __shared__ __align__(16) unsigned short Lb[2][BN * 64];

  int tid = threadIdx.x;
  int wave = tid >> 6, lane = tid & 63;
  int lrow = lane & 15, lq = lane >> 4;
  int wr = (wave >> 1) * (MI * 16), wc = (wave & 1) * (NI * 16);
  f32x4 acc[MI][NI] = {};

  int kmask = (1 << J.lgSteps) - 1;
  int nt = J.nt;

  auto stage_both = [&](int t, int buf) {
    int seg = t >> J.lgSteps;
    const unsigned short* Ab = (seg == 0) ? J.A0 : ((seg == 1) ? J.A1 : J.A2);
    const unsigned short* GA = Ab + (size_t)bm * J.Astride + (size_t)((t & kmask) << 6);
    const unsigned short* GB = J.Bt + (size_t)bn * J.Bstride + (size_t)t * 64;
#pragma unroll
    for (int p = 0; p < MI; ++p) {     // A: BM*64 bf16 = MI*256 slots of 16B
      int s = p * 256 + tid;
      gload16(GA + (size_t)(s >> 3) * J.Astride + (s & 7) * 8,
              &La[buf][(size_t)(p * 256 + wave * 64) * 8]);
    }
#pragma unroll
    for (int p = 0; p < NI; ++p) {     // B: BN*64 bf16 = NI*256 slots
      int s = p * 256 + tid;
      gload16(GB + (size_t)(s >> 3) * J.Bstride + (s & 7) * 8,
              &Lb[buf][(size_t)(p * 256 + wave * 64) * 8]);
    }
  };

  stage_both(0, 0);
  if (nt > 1) stage_both(1, 1);

  for (int t = 0; t < nt; ++t) {
    // wait until THIS tile's DMA landed; next tile's (MI+NI) stay in flight
    if (t + 1 < nt) {
      if constexpr (MI + NI == 8)      asm volatile("s_waitcnt vmcnt(8)" ::: "memory");
      else if constexpr (MI + NI == 6) asm volatile("s_waitcnt vmcnt(6)" ::: "memory");
      else                             asm volatile("s_waitcnt vmcnt(4)" ::: "memory");
    } else {
      asm volatile("s_waitcnt vmcnt(0)" ::: "memory");
    }
    SBAR();                              // all waves' tile-t data visible
    int cur = t & 1;
#pragma unroll
    for (int kc = 0; kc < 2; ++kc) {
      int kb = kc * 4 + lq;
      bf16x8 af[MI], bv[NI];
#pragma unroll
      for (int mi = 0; mi < MI; ++mi) {
        int r = wr + mi * 16 + lrow;
        af[mi] = *(const bf16x8*)&La[cur][r * 64 + ((kb + r) & 7) * 8];
      }
#pragma unroll
      for (int ni = 0; ni < NI; ++ni) {
        int r = wc + ni * 16 + lrow;
        bv[ni] = *(const bf16x8*)&Lb[cur][r * 64 + ((kb + r) & 7) * 8];
      }
#pragma unroll
      for (int mi = 0; mi < MI; ++mi)
#pragma unroll
        for (int ni = 0; ni < NI; ++ni)
          acc[mi][ni] = __builtin_amdgcn_mfma_f32_16x16x32_bf16(af[mi], bv[ni], acc[mi][ni], 0, 0, 0);
    }
    SBAR();                              // all waves done reading buf[cur]
    if (t + 2 < nt) stage_both(t + 2, cur);   // refill freed buffer
  }

  // epilogue: C/D layout col=lane&15, row=lq*4+reg
#pragma unroll
  for (int mi = 0; mi < MI; ++mi) {
#pragma unroll
    for (int ni = 0; ni < NI; ++ni) {
      int gn = bn + wc + ni * 16 + lrow;
      float bvs = J.bias ? J.bias[gn] : 0.f;
      int gm0 = bm + wr + mi * 16 + lq * 4;
      if (J.mode == 1) {
#pragma unroll
        for (int r = 0; r < 4; ++r)
          J.Cf[(size_t)(gm0 + r) * J.Cstride + gn] = acc[mi][ni][r] + bvs;
      } else if (J.mode == 0) {
#pragma unroll
        for (int r = 0; r < 4; ++r)
          J.Cb[(size_t)(gm0 + r) * J.Cstride + gn] = f2bf(acc[mi][ni][r] + bvs);
      } else {
        // mode 2: store so that row-major [M][N] reads as a swizzled B panel
        // (N plays the role of K for the consumer GEMM)
#pragma unroll
        for (int r = 0; r < 4; ++r) {
          int row = gm0 + r;
          int col = (gn & ~63) | (((((gn >> 3) & 7) + row) & 7) << 3) | (gn & 7);
          J.Cb[(size_t)row * J.Cstride + col] = f2bf(acc[mi][ni][r] + bvs);
        }
      }
    }
  }
}

// ==== fused scores + separable softmax + ctx + output ======================
// ws[l,i] = softmax_i(cc q.t_key[i]);  wt[l,j] = softmax_j(cc q.s_key[j])
// out[l,h] = relu(P[l,h] + sum_i ws[l,i] sv'[i,h] + sum_j wt[l,j] tv'[j,h])
__global__ __launch_bounds__(256) void attn_fused(
    const unsigned short* __restrict__ qh, const unsigned short* __restrict__ s_key,
    const unsigned short* __restrict__ t_key, const unsigned short* __restrict__ svp,
    const unsigned short* __restrict__ tvp, const float* __restrict__ P,
    float* __restrict__ out) {
  __shared__ float wlT[2][36][32];   // [mat][j][l], 9.2 KB
  int b = blockIdx.x, lc = blockIdx.y;
  int tid = threadIdx.x, wave = tid >> 6, lane = tid & 63;
  int lrow = lane & 15, lq = lane >> 4;
  int mat = wave >> 1, rh = wave & 1;
  int row0 = b * 128 + lc * 32 + rh * 16;
  const unsigned short* qp = qh + (size_t)row0 * 512;
  const unsigned short* key = (mat ? s_key : t_key) + (size_t)b * 36 * 512;
  f32x4 acc[3] = {};
  for (int kc = 0; kc < 16; ++kc) {
    int k = kc * 32 + lq * 8;
    bf16x8 af = *(const bf16x8*)(qp + (size_t)lrow * 512 + k);
#pragma unroll
    for (int nf = 0; nf < 3; ++nf) {
      int n = nf * 16 + lrow; if (n > 35) n = 35;   // clamp; masked in softmax
      bf16x8 bv = *(const bf16x8*)(key + (size_t)n * 512 + k);
      acc[nf] = __builtin_amdgcn_mfma_f32_16x16x32_bf16(af, bv, acc[nf], 0, 0, 0);
    }
  }
  const float ccs = 0.022097086912079608f;   // 0.5 / sqrt(512)
  float ex[3][4];
#pragma unroll
  for (int r = 0; r < 4; ++r) {
    float a0 = acc[0][r] * ccs;
    float a1 = acc[1][r] * ccs;
    float a2 = (lrow < 4) ? acc[2][r] * ccs : -1e30f;
    float mx = fmaxf(fmaxf(a0, a1), a2);
    for (int s = 1; s < 16; s <<= 1) mx = fmaxf(mx, __shfl_xor(mx, s));
    float e0 = __expf(a0 - mx), e1 = __expf(a1 - mx);
    float e2 = (lrow < 4) ? __expf(a2 - mx) : 0.f;
    float sum = e0 + e1 + e2;
    for (int s = 1; s < 16; s <<= 1) sum += __shfl_xor(sum, s);
    float inv = 1.f / sum;
    ex[0][r] = e0 * inv; ex[1][r] = e1 * inv; ex[2][r] = e2 * inv;
  }
#pragma unroll
  for (int nf = 0; nf < 3; ++nf) {
    int col = nf * 16 + lrow;
    if (col < 36) {
#pragma unroll
      for (int r = 0; r < 4; ++r)
        wlT[mat][col][rh * 16 + lq * 4 + r] = ex[nf][r];
    }
  }
  __syncthreads();

  // ctx phase: thread (lgrp, hgrp) handles 8 l-rows x 8 h, both mats summed
  int lgrp = tid >> 6, hgrp = tid & 63;
  float a2[8][8] = {};
#pragma unroll
  for (int m = 0; m < 2; ++m) {
    const unsigned short* V = (m ? tvp : svp) + (size_t)b * 36 * 512;
    for (int j = 0; j < 36; ++j) {
      f32x4 wa = *(const f32x4*)&wlT[m][j][lgrp * 8];       // broadcast
      f32x4 wb = *(const f32x4*)&wlT[m][j][lgrp * 8 + 4];
      bf16x8 v = *(const bf16x8*)(V + (size_t)j * 512 + hgrp * 8);
      float vf[8];
#pragma unroll
      for (int hi = 0; hi < 8; ++hi) vf[hi] = bf2f((unsigned short)v[hi]);
#pragma unroll
      for (int li = 0; li < 4; ++li)
#pragma unroll
        for (int hi = 0; hi < 8; ++hi) a2[li][hi] += wa[li] * vf[hi];
#pragma unroll
      for (int li = 0; li < 4; ++li)
#pragma unroll
        for (int hi = 0; hi < 8; ++hi) a2[4 + li][hi] += wb[li] * vf[hi];
    }
  }
#pragma unroll
  for (int li = 0; li < 8; ++li) {
    int R = b * 128 + lc * 32 + lgrp * 8 + li;
    const float* Pp = P + (size_t)R * 512 + hgrp * 8;
    float* op = out + (size_t)R * 512 + hgrp * 8;
    f32x4 p0 = *(const f32x4*)Pp;
    f32x4 p1 = *(const f32x4*)(Pp + 4);
    f32x4 o0, o1;
#pragma unroll
    for (int hi = 0; hi < 4; ++hi) {
      o0[hi] = fmaxf(p0[hi] + a2[li][hi], 0.f);
      o1[hi] = fmaxf(p1[hi] + a2[li][4 + hi], 0.f);
    }
    *(f32x4*)op = o0;
    *(f32x4*)(op + 4) = o1;
  }
}

// ---------------------------------------------------------------------------
extern "C" void kernel_launch(void* const* d_in, const int* in_sizes, int n_in,
                              void* d_out, int out_size, void* d_ws, size_t ws_size,
                              hipStream_t stream) {
  (void)in_sizes; (void)n_in; (void)out_size; (void)ws_size;
  const float* query = (const float*)d_in[0];
  const float* src   = (const float*)d_in[1];
  const float* trg   = (const float*)d_in[2];
  const float* Wq  = (const float*)d_in[3];  const float* bq  = (const float*)d_in[4];
  const float* Wsk = (const float*)d_in[5];  const float* bs  = (const float*)d_in[6];
  const float* Wtk = (const float*)d_in[7];  const float* bt  = (const float*)d_in[8];
  const float* Wsv = (const float*)d_in[9];  const float* bsv = (const float*)d_in[10];
  const float* Wtv = (const float*)d_in[11]; const float* btv = (const float*)d_in[12];
  const float* Wo  = (const float*)d_in[13]; const float* bo  = (const float*)d_in[14];
  (void)bsv; (void)btv;
  // NOTE: bsv/btv are additive constants to s_value/t_value rows; after the
  // softmax weighted sum (weights sum to 1) they contribute bsv@Wo2 + btv@Wo3,
  // a constant 512-vector. We fold them via bias2 = bo + bsv@Wo2 + btv@Wo3
  // computed in the wprod kernel's extra job... simpler: keep them exact by
  // adding bsv/btv as bias to the value' projections IS WRONG (they'd be
  // multiplied by Wsv'... no). Instead fold into P's bias below via a tiny
  // device-side pass is overkill -- we instead add bsv/btv contribution
  // exactly: sv' rows get bias (bsv @ Wo2) which is constant per h. We
  // compute it inside wprod: C row r bias = sum_h bsv[h] * ... not per-row.
  // Cleanest exact fold: attn adds ws@(sv'+bsv@Wo2_row)... Since sum_i ws=1,
  // total = ws@sv' + bsv@Wo2. We add bsv@Wo2 + btv@Wo3 into P via the P job's
  // bias: bias_P[gn] = bo[gn] + sum_h bsv[h] Wo2[h][gn] + sum_h btv[h] Wo3[h][gn].
  // That requires a 512-dot per gn -- do it in a tiny kernel before proj.

  // workspace (bf16 shorts unless noted)
  unsigned short* WqT    = (unsigned short*)d_ws;     // 512*512
  unsigned short* WsT    = WqT  + 512 * 512;          // 512*2048
  unsigned short* WtT    = WsT  + 512 * 2048;         // 512*2048
  unsigned short* WoT    = WtT  + 512 * 2048;         // 512*1536
  unsigned short* WsvA   = WoT  + 512 * 1536;         // 2048*512 row-major swz
  unsigned short* WtvA   = WsvA + 2048 * 512;
  unsigned short* WsvPT  = WtvA + 2048 * 512;         // 512*2048 (B-panel swz)
  unsigned short* WtvPT  = WsvPT + 512 * 2048;
  unsigned short* queryB = WtvPT + 512 * 2048;        // 4096*512 swz
  unsigned short* srcB   = queryB + 4096 * 512;       // 1152*2048 swz
  unsigned short* trgB   = srcB + 1152 * 2048;
  unsigned short* qh     = trgB + 1152 * 2048;        // 4096*512
  unsigned short* s_key  = qh + 4096 * 512;           // 1152*512
  unsigned short* t_key  = s_key + 1152 * 512;
  unsigned short* svp    = t_key + 1152 * 512;        // 1152*512 value' rows
  unsigned short* tvp    = svp + 1152 * 512;
  float* P     = (float*)(tvp + 1152 * 512);          // 4096*512 f32
  float* biasP = P + (size_t)4096 * 512;              // 512 f32
  float* out = (float*)d_out;

  // 1. prep: 4 weight transposes + 5 row-major converts
  PrepJobs pj;
  const float* psrc[9] = { Wq, Wsk, Wtk, Wo, query, src, trg, Wsv, Wtv };
  unsigned short* pdst[9] = { WqT, WsT, WtT, WoT, queryB, srcB, trgB, WsvA, WtvA };
  int pK[9]    = { 512, 2048, 2048, 1536, 512, 2048, 2048, 512, 512 };
  int ptype[9] = { 0, 0, 0, 0, 1, 1, 1, 1, 1 };
  int prows[9] = { 0, 0, 0, 0, 4096, 1152, 1152, 2048, 2048 };
  int pbase = 0;
  for (int i = 0; i < 9; ++i) {
    pj.src[i] = psrc[i]; pj.dst[i] = pdst[i]; pj.K[i] = pK[i]; pj.type[i] = ptype[i];
    pj.base[i] = pbase;
    pbase += ptype[i] ? (prows[i] / 64) * (pK[i] / 64) : (pK[i] / 64) * 8;
  }
  prep<<<pbase, 256, 0, stream>>>(pj);

  // 1b. biasP[n] = bo[n] + bsv.Wo2[:,n] + btv.Wo3[:,n]  (exact bias fold)
  // tiny kernel: 512 outputs, 2x512-dot each
  {
    struct BiasK {
      static __global__ void run(const float* bo_, const float* bsv_,
                                 const float* btv_, const float* Wo_,
                                 float* biasP_) {
        int n = blockIdx.x * 64 + (threadIdx.x & 63);
        int half = threadIdx.x >> 6;   // 4 waves: 2 halves x 2 chunks
        __shared__ float partial[4][64];
        float s = 0.f;
        const float* vb = half & 1 ? btv_ : bsv_;
        const float* W = Wo_ + (half & 1 ? 1024 : 512) + n;
        for (int h = (half >> 1) * 256; h < (half >> 1) * 256 + 256; ++h)
          s += vb[h] * W[(size_t)h * 1536];
        partial[half][threadIdx.x & 63] = s;
        __syncthreads();
        if (half == 0) {
          float t = partial[0][threadIdx.x] + partial[1][threadIdx.x] +
                    partial[2][threadIdx.x] + partial[3][threadIdx.x];
          biasP_[n] = bo_[n] + t;
        }
      }
    };
    hipLaunchKernelGGL(BiasK::run, dim3(8), dim3(256), 0, stream,
                       bo, bsv, btv, Wo, biasP);
  }

  // 2. wprod: Wsv'T = Wo2T @ WsvA^T, Wtv'T = Wo3T @ WtvA^T  (mode-2 output)
  {
    GBatch wb;
    wb.swz = 1;
    GJob& a = wb.j[0];
    a.A0 = WoT + 512; a.A1 = a.A0; a.A2 = a.A0;       // Wo2T rows, Astride 1536
    a.Bt = WsvA; a.bias = nullptr; a.Cb = WsvPT; a.Cf = nullptr;
    a.Astride = 1536; a.Bstride = 512; a.Cstride = 2048;
    a.nTilesN = 16; a.nt = 8; a.lgSteps = 3; a.mode = 2; a.tileBase = 0;
    GJob& b2 = wb.j[1];
    b2 = a;
    b2.A0 = WoT + 1024; b2.A1 = b2.A0; b2.A2 = b2.A0;
    b2.Bt = WtvA; b2.Cb = WtvPT;
    b2.tileBase = 128;
    for (int i = 2; i < 7; ++i) { wb.j[i] = b2; wb.j[i].tileBase = 0x7fffffff; }
    wb.njobs = 2;
    gemm_pipe<2, 4><<<256, 256, 0, stream>>>(wb);     // 256 blocks
  }

  // 3. merged projections: s_key, t_key, sv', tv', qh, P  (800 blocks)
  {
    GBatch pb;
    pb.swz = 0;
    int base = 0;
    const unsigned short* Aarr[4] = { srcB, trgB, srcB, trgB };
    const unsigned short* Barr[4] = { WsT, WtT, WsvPT, WtvPT };
    const float* biasArr[4] = { bs, bt, nullptr, nullptr };
    unsigned short* Carr[4] = { s_key, t_key, svp, tvp };
    for (int i = 0; i < 4; ++i) {             // 4 big K=2048 jobs, 72 tiles each
      GJob& j = pb.j[i];
      j.A0 = Aarr[i]; j.A1 = Aarr[i]; j.A2 = Aarr[i];
      j.Bt = Barr[i]; j.bias = biasArr[i]; j.Cb = Carr[i]; j.Cf = nullptr;
      j.Astride = 2048; j.Bstride = 2048; j.Cstride = 512;
      j.nTilesN = 4; j.nt = 32; j.lgSteps = 5; j.mode = 0;
      j.tileBase = base; base += (1152 / 64) * 4;
    }
    {                                          // qh = query@Wq + bq, 256 tiles
      GJob& j = pb.j[4];
      j.A0 = queryB; j.A1 = queryB; j.A2 = queryB;
      j.Bt = WqT; j.bias = bq; j.Cb = qh; j.Cf = nullptr;
      j.Astride = 512; j.Bstride = 512; j.Cstride = 512;
      j.nTilesN = 4; j.nt = 8; j.lgSteps = 3; j.mode = 0;
      j.tileBase = base; base += (4096 / 64) * 4;
    }
    {                                          // P = query@Wo1 + biasP, 256 tiles
      GJob& j = pb.j[5];
      j.A0 = queryB; j.A1 = queryB; j.A2 = queryB;
      j.Bt = WoT; j.bias = biasP; j.Cb = nullptr; j.Cf = P;
      j.Astride = 512; j.Bstride = 1536; j.Cstride = 512;
      j.nTilesN = 4; j.nt = 8; j.lgSteps = 3; j.mode = 1;
      j.tileBase = base; base += (4096 / 64) * 4;
    }
    pb.j[6] = pb.j[5]; pb.j[6].tileBase = 0x7fffffff;
    pb.njobs = 6;
    gemm_pipe<2, 4><<<base, 256, 0, stream>>>(pb);   // 800 blocks
  }

  // 4. fused scores + softmax + ctx + epilogue -> out (128 blocks)
  attn_fused<<<dim3(32, 4), 256, 0, stream>>>(qh, s_key, t_key, svp, tvp, P, out);
}

// Round 10
// 98.963 us; speedup vs baseline: 1.2790x; 1.2790x over previous
//
#include <hip/hip_runtime.h>
#include <hip/hip_bf16.h>
#include <math.h>

#define DEVI __device__ __forceinline__

typedef __attribute__((ext_vector_type(4))) float f32x4;
typedef __attribute__((ext_vector_type(8))) short bf16x8;

DEVI unsigned short f2bf(float f) {
  union { float f; unsigned int u; } v; v.f = f;
  return (unsigned short)((v.u + 0x7FFFu + ((v.u >> 16) & 1u)) >> 16);
}
DEVI float bf2f(unsigned short s) {
  union { unsigned int u; float f; } v; v.u = ((unsigned int)s) << 16; return v.f;
}
DEVI bf16x8 pack8(f32x4 a, f32x4 b) {
  bf16x8 r;
  r[0] = (short)f2bf(a[0]); r[1] = (short)f2bf(a[1]);
  r[2] = (short)f2bf(a[2]); r[3] = (short)f2bf(a[3]);
  r[4] = (short)f2bf(b[0]); r[5] = (short)f2bf(b[1]);
  r[6] = (short)f2bf(b[2]); r[7] = (short)f2bf(b[3]);
  return r;
}
DEVI void gload16(const unsigned short* g, unsigned short* l) {
  __builtin_amdgcn_global_load_lds(
      (const __attribute__((address_space(1))) unsigned int*)g,
      (__attribute__((address_space(3))) unsigned int*)l, 16, 0, 0);
}
// raw workgroup barrier WITHOUT the implicit vmcnt(0) drain of __syncthreads
#define SBAR() do { asm volatile("" ::: "memory"); \
                    __builtin_amdgcn_s_barrier();  \
                    asm volatile("" ::: "memory"); } while (0)

// ==== prep: weights f32[K][512] -> bf16 [512][K] swz ; f32[M][K] -> bf16 [M][K] swz
// swizzle: within each 64-elem k-group, kblock kb of row n stored at ((kb+n)&7).
struct PrepJobs {
  const float* src[9];
  unsigned short* dst[9];
  int K[9];
  int base[9];
  int type[9];   // 0 = weight transpose (64x64 tiles), 1 = row-major convert
};

__global__ __launch_bounds__(256) void prep(PrepJobs J) {
  __shared__ float t[64][65];   // 16.6 KB
  int tile = blockIdx.x;
  int job = 0;
  while (job < 8 && tile >= J.base[job + 1]) ++job;
  int tl = tile - J.base[job];
  int K = J.K[job];
  if (J.type[job] == 0) {
    int tn = tl & 7, tk = tl >> 3;   // 512/64 = 8 n-tiles
    int x = threadIdx.x & 63, y = threadIdx.x >> 6;
    const float* s = J.src[job];
    int k0 = tk * 64, n0 = tn * 64;
#pragma unroll
    for (int yy = y; yy < 64; yy += 4)
      t[yy][x] = s[(size_t)(k0 + yy) * 512 + n0 + x];
    __syncthreads();
    unsigned short* d = J.dst[job];
    int kb = (x >> 3) & 7, ko = x & 7;   // k = k0 + x, k0 % 64 == 0
#pragma unroll
    for (int yy = y; yy < 64; yy += 4) {
      int n = n0 + yy;
      int kswz = k0 + (((kb + n) & 7) << 3) + ko;
      d[(size_t)n * K + kswz] = f2bf(t[x][yy]);
    }
  } else {
    int nk = K >> 6;
    int rt = tl / nk;
    int r0 = rt * 64, k0 = (tl - rt * nk) * 64;
    int r = threadIdx.x >> 2, kq = threadIdx.x & 3;
    int row = r0 + r;
    const float* s = J.src[job] + (size_t)row * K + k0 + kq * 16;
    f32x4 a0 = *(const f32x4*)s;
    f32x4 a1 = *(const f32x4*)(s + 4);
    f32x4 a2 = *(const f32x4*)(s + 8);
    f32x4 a3 = *(const f32x4*)(s + 12);
    unsigned short* d = J.dst[job] + (size_t)row * K + k0;
    int kb0 = kq * 2;
    *(bf16x8*)(d + ((kb0 + row) & 7) * 8) = pack8(a0, a1);
    *(bf16x8*)(d + ((kb0 + 1 + row) & 7) * 8) = pack8(a2, a3);
  }
}

// ==== biask: vb-dot-columns of Wo2/Wo3, massively parallel =================
// outv[o] for o<512:  sum_h bsv[h]*Wo[h][512+o]
//         for o>=512: sum_h btv[h]*Wo[h][1024+(o-512)]
__global__ __launch_bounds__(256) void biask(const float* __restrict__ bsv,
                                             const float* __restrict__ btv,
                                             const float* __restrict__ Wo,
                                             float* __restrict__ outv) {
  int o = blockIdx.x;           // 1024 blocks
  int which = o >> 9, n = o & 511;
  const float* vb = which ? btv : bsv;
  const float* W = Wo + 512 + which * 512 + n;
  float s = 0.f;
  for (int h = threadIdx.x; h < 512; h += 256)
    s += vb[h] * W[(size_t)h * 1536];
#pragma unroll
  for (int off = 32; off; off >>= 1) s += __shfl_xor(s, off);
  __shared__ float red[4];
  if ((threadIdx.x & 63) == 0) red[threadIdx.x >> 6] = s;
  __syncthreads();
  if (threadIdx.x == 0) outv[o] = red[0] + red[1] + red[2] + red[3];
}

// ==== MFMA GEMM, counted-vmcnt double-buffer, templated tile ===============
// BM = MI*32, BN = NI*32, BK = 64; 4 waves (2m x 2n), wave tile (MI*16)x(NI*16).
// C[M][N] = A @ B (+ bias). A/B bf16 pre-swizzled; staging is pure
// global_load_lds DMA; s_waitcnt vmcnt(MI+NI) keeps next tile in flight.
// mode 0: bf16 row-major out. mode 1: f32 row-major out. mode 2: bf16 out
// with per-row k-group swizzle (so C can be consumed as a B operand later).
struct GJob {
  const unsigned short* A0;
  const unsigned short* Bt;
  const float* bias;        // may be nullptr
  unsigned short* Cb;
  float* Cf;
  int Astride, Bstride, Cstride, nTilesN, nt, mode, tileBase;
};
struct GBatch { GJob j[7]; int njobs; int swz; };

template <int MI, int NI>
__global__ __launch_bounds__(256) void gemm_pipe(GBatch batch) {
  constexpr int BM = MI * 32, BN = NI * 32;
  int gt = blockIdx.x;
  if (batch.swz) {                         // XCD swizzle only for homogeneous grids
    int cpx = gridDim.x >> 3;
    gt = (blockIdx.x & 7) * cpx + (blockIdx.x >> 3);
  }
  int job = 0;
#pragma unroll
  for (int i = 1; i < 7; ++i)
    if (i < batch.njobs && gt >= batch.j[i].tileBase) job = i;
  GJob J = batch.j[job];
  int tl = gt - J.tileBase;
  int bm = (tl / J.nTilesN) * BM, bn = (tl % J.nTilesN) * BN;

  __shared__ __align__(16) unsigned short La[2][BM * 64];
  __shared__ __align__(16) unsigned short Lb[2][BN * 64];

  int tid = threadIdx.x;
  int wave = tid >> 6, lane = tid & 63;
  int lrow = lane & 15, lq = lane >> 4;
  int wr = (wave >> 1) * (MI * 16), wc = (wave & 1) * (NI * 16);
  f32x4 acc[MI][NI] = {};

  int nt = J.nt;

  auto stage_both = [&](int t, int buf) {
    const unsigned short* GA = J.A0 + (size_t)bm * J.Astride + (size_t)(t << 6);
    const unsigned short* GB = J.Bt + (size_t)bn * J.Bstride + (size_t)(t << 6);
#pragma unroll
    for (int p = 0; p < MI; ++p) {     // A: BM*64 bf16 = MI*256 slots of 16B
      int s = p * 256 + tid;
      gload16(GA + (size_t)(s >> 3) * J.Astride + (s & 7) * 8,
              &La[buf][(size_t)(p * 256 + wave * 64) * 8]);
    }
#pragma unroll
    for (int p = 0; p < NI; ++p) {     // B: BN*64 bf16 = NI*256 slots
      int s = p * 256 + tid;
      gload16(GB + (size_t)(s >> 3) * J.Bstride + (s & 7) * 8,
              &Lb[buf][(size_t)(p * 256 + wave * 64) * 8]);
    }
  };

  stage_both(0, 0);
  if (nt > 1) stage_both(1, 1);

  for (int t = 0; t < nt; ++t) {
    // wait until THIS tile's DMA landed; next tile's (MI+NI) stay in flight
    if (t + 1 < nt) {
      if constexpr (MI + NI == 8)      asm volatile("s_waitcnt vmcnt(8)" ::: "memory");
      else if constexpr (MI + NI == 6) asm volatile("s_waitcnt vmcnt(6)" ::: "memory");
      else                             asm volatile("s_waitcnt vmcnt(4)" ::: "memory");
    } else {
      asm volatile("s_waitcnt vmcnt(0)" ::: "memory");
    }
    SBAR();                              // all waves' tile-t data visible
    int cur = t & 1;
#pragma unroll
    for (int kc = 0; kc < 2; ++kc) {
      int kb = kc * 4 + lq;
      bf16x8 af[MI], bv[NI];
#pragma unroll
      for (int mi = 0; mi < MI; ++mi) {
        int r = wr + mi * 16 + lrow;
        af[mi] = *(const bf16x8*)&La[cur][r * 64 + ((kb + r) & 7) * 8];
      }
#pragma unroll
      for (int ni = 0; ni < NI; ++ni) {
        int r = wc + ni * 16 + lrow;
        bv[ni] = *(const bf16x8*)&Lb[cur][r * 64 + ((kb + r) & 7) * 8];
      }
#pragma unroll
      for (int mi = 0; mi < MI; ++mi)
#pragma unroll
        for (int ni = 0; ni < NI; ++ni)
          acc[mi][ni] = __builtin_amdgcn_mfma_f32_16x16x32_bf16(af[mi], bv[ni], acc[mi][ni], 0, 0, 0);
    }
    SBAR();                              // all waves done reading buf[cur]
    if (t + 2 < nt) stage_both(t + 2, cur);   // refill freed buffer
  }

  // epilogue: C/D layout col=lane&15, row=lq*4+reg
#pragma unroll
  for (int mi = 0; mi < MI; ++mi) {
#pragma unroll
    for (int ni = 0; ni < NI; ++ni) {
      int gn = bn + wc + ni * 16 + lrow;
      float bvs = J.bias ? J.bias[gn] : 0.f;
      int gm0 = bm + wr + mi * 16 + lq * 4;
      if (J.mode == 1) {
#pragma unroll
        for (int r = 0; r < 4; ++r)
          J.Cf[(size_t)(gm0 + r) * J.Cstride + gn] = acc[mi][ni][r] + bvs;
      } else if (J.mode == 0) {
#pragma unroll
        for (int r = 0; r < 4; ++r)
          J.Cb[(size_t)(gm0 + r) * J.Cstride + gn] = f2bf(acc[mi][ni][r] + bvs);
      } else {
        // mode 2: store so that row-major [M][N] reads as a swizzled B panel
#pragma unroll
        for (int r = 0; r < 4; ++r) {
          int row = gm0 + r;
          int col = (gn & ~63) | (((((gn >> 3) & 7) + row) & 7) << 3) | (gn & 7);
          J.Cb[(size_t)row * J.Cstride + col] = f2bf(acc[mi][ni][r] + bvs);
        }
      }
    }
  }
}

// ==== fused scores + separable softmax + ctx + output ======================
// ws[l,i] = softmax_i(cc q.t_key[i]);  wt[l,j] = softmax_j(cc q.s_key[j])
// out[l,h] = relu(P[l,h] + sum_i ws[l,i] svp[i,h] + sum_j wt[l,j] tvp[j,h])
__global__ __launch_bounds__(256) void attn_fused(
    const unsigned short* __restrict__ qh, const unsigned short* __restrict__ s_key,
    const unsigned short* __restrict__ t_key, const float* __restrict__ svp,
    const float* __restrict__ tvp, const float* __restrict__ P,
    float* __restrict__ out) {
  __shared__ float wlT[2][36][32];   // [mat][j][l], 9.2 KB
  int b = blockIdx.x, lc = blockIdx.y;
  int tid = threadIdx.x, wave = tid >> 6, lane = tid & 63;
  int lrow = lane & 15, lq = lane >> 4;
  int mat = wave >> 1, rh = wave & 1;
  int row0 = b * 128 + lc * 32 + rh * 16;
  const unsigned short* qp = qh + (size_t)row0 * 512;
  const unsigned short* key = (mat ? s_key : t_key) + (size_t)b * 36 * 512;
  f32x4 acc[3] = {};
  for (int kc = 0; kc < 16; ++kc) {
    int k = kc * 32 + lq * 8;
    bf16x8 af = *(const bf16x8*)(qp + (size_t)lrow * 512 + k);
#pragma unroll
    for (int nf = 0; nf < 3; ++nf) {
      int n = nf * 16 + lrow; if (n > 35) n = 35;   // clamp; masked in softmax
      bf16x8 bv = *(const bf16x8*)(key + (size_t)n * 512 + k);
      acc[nf] = __builtin_amdgcn_mfma_f32_16x16x32_bf16(af, bv, acc[nf], 0, 0, 0);
    }
  }
  const float ccs = 0.022097086912079608f;   // 0.5 / sqrt(512)
  float ex[3][4];
#pragma unroll
  for (int r = 0; r < 4; ++r) {
    float a0 = acc[0][r] * ccs;
    float a1 = acc[1][r] * ccs;
    float a2 = (lrow < 4) ? acc[2][r] * ccs : -1e30f;
    float mx = fmaxf(fmaxf(a0, a1), a2);
    for (int s = 1; s < 16; s <<= 1) mx = fmaxf(mx, __shfl_xor(mx, s));
    float e0 = __expf(a0 - mx), e1 = __expf(a1 - mx);
    float e2 = (lrow < 4) ? __expf(a2 - mx) : 0.f;
    float sum = e0 + e1 + e2;
    for (int s = 1; s < 16; s <<= 1) sum += __shfl_xor(sum, s);
    float inv = 1.f / sum;
    ex[0][r] = e0 * inv; ex[1][r] = e1 * inv; ex[2][r] = e2 * inv;
  }
#pragma unroll
  for (int nf = 0; nf < 3; ++nf) {
    int col = nf * 16 + lrow;
    if (col < 36) {
#pragma unroll
      for (int r = 0; r < 4; ++r)
        wlT[mat][col][rh * 16 + lq * 4 + r] = ex[nf][r];
    }
  }
  __syncthreads();

  // ctx phase: thread (lgrp, hgrp) handles 8 l-rows x 8 h, both mats summed
  int lgrp = tid >> 6, hgrp = tid & 63;
  float a2[8][8] = {};
#pragma unroll
  for (int m = 0; m < 2; ++m) {
    const float* V = (m ? tvp : svp) + (size_t)b * 36 * 512;
    for (int j = 0; j < 36; ++j) {
      f32x4 wa = *(const f32x4*)&wlT[m][j][lgrp * 8];       // broadcast
      f32x4 wb = *(const f32x4*)&wlT[m][j][lgrp * 8 + 4];
      const float* vp = V + (size_t)j * 512 + hgrp * 8;
      f32x4 v0 = *(const f32x4*)vp;
      f32x4 v1 = *(const f32x4*)(vp + 4);
      float vf[8];
#pragma unroll
      for (int hi = 0; hi < 4; ++hi) { vf[hi] = v0[hi]; vf[4 + hi] = v1[hi]; }
#pragma unroll
      for (int li = 0; li < 4; ++li)
#pragma unroll
        for (int hi = 0; hi < 8; ++hi) a2[li][hi] += wa[li] * vf[hi];
#pragma unroll
      for (int li = 0; li < 4; ++li)
#pragma unroll
        for (int hi = 0; hi < 8; ++hi) a2[4 + li][hi] += wb[li] * vf[hi];
    }
  }
#pragma unroll
  for (int li = 0; li < 8; ++li) {
    int R = b * 128 + lc * 32 + lgrp * 8 + li;
    const float* Pp = P + (size_t)R * 512 + hgrp * 8;
    float* op = out + (size_t)R * 512 + hgrp * 8;
    f32x4 p0 = *(const f32x4*)Pp;
    f32x4 p1 = *(const f32x4*)(Pp + 4);
    f32x4 o0, o1;
#pragma unroll
    for (int hi = 0; hi < 4; ++hi) {
      o0[hi] = fmaxf(p0[hi] + a2[li][hi], 0.f);
      o1[hi] = fmaxf(p1[hi] + a2[li][4 + hi], 0.f);
    }
    *(f32x4*)op = o0;
    *(f32x4*)(op + 4) = o1;
  }
}

// ---------------------------------------------------------------------------
extern "C" void kernel_launch(void* const* d_in, const int* in_sizes, int n_in,
                              void* d_out, int out_size, void* d_ws, size_t ws_size,
                              hipStream_t stream) {
  (void)in_sizes; (void)n_in; (void)out_size; (void)ws_size;
  const float* query = (const float*)d_in[0];
  const float* src   = (const float*)d_in[1];
  const float* trg   = (const float*)d_in[2];
  const float* Wq  = (const float*)d_in[3];  const float* bq  = (const float*)d_in[4];
  const float* Wsk = (const float*)d_in[5];  const float* bs  = (const float*)d_in[6];
  const float* Wtk = (const float*)d_in[7];  const float* bt  = (const float*)d_in[8];
  const float* Wsv = (const float*)d_in[9];  const float* bsv = (const float*)d_in[10];
  const float* Wtv = (const float*)d_in[11]; const float* btv = (const float*)d_in[12];
  const float* Wo  = (const float*)d_in[13]; const float* bo  = (const float*)d_in[14];

  // workspace (bf16 shorts unless noted)
  unsigned short* WqT    = (unsigned short*)d_ws;     // 512*512
  unsigned short* WsT    = WqT  + 512 * 512;          // 512*2048
  unsigned short* WtT    = WsT  + 512 * 2048;         // 512*2048
  unsigned short* WoT    = WtT  + 512 * 2048;         // 512*1536
  unsigned short* WsvA   = WoT  + 512 * 1536;         // 2048*512 row-major swz
  unsigned short* WtvA   = WsvA + 2048 * 512;
  unsigned short* WsvPT  = WtvA + 2048 * 512;         // 512*2048 (B-panel swz)
  unsigned short* WtvPT  = WsvPT + 512 * 2048;
  unsigned short* queryB = WtvPT + 512 * 2048;        // 4096*512 swz
  unsigned short* srcB   = queryB + 4096 * 512;       // 1152*2048 swz
  unsigned short* trgB   = srcB + 1152 * 2048;
  unsigned short* qh     = trgB + 1152 * 2048;        // 4096*512
  unsigned short* s_key  = qh + 4096 * 512;           // 1152*512
  unsigned short* t_key  = s_key + 1152 * 512;
  float* svp   = (float*)(t_key + 1152 * 512);        // 1152*512 f32 value'
  float* tvp   = svp + 1152 * 512;
  float* P     = tvp + 1152 * 512;                    // 4096*512 f32
  float* biasV = P + (size_t)4096 * 512;              // 1024 f32: [bsvP|btvP]
  float* out = (float*)d_out;

  // 1. biask: bsvP = bsv@Wo2, btvP = btv@Wo3  (1024 blocks, ~2us)
  biask<<<1024, 256, 0, stream>>>(bsv, btv, Wo, biasV);

  // 2. prep: 4 weight transposes + 5 row-major converts
  PrepJobs pj;
  const float* psrc[9] = { Wq, Wsk, Wtk, Wo, query, src, trg, Wsv, Wtv };
  unsigned short* pdst[9] = { WqT, WsT, WtT, WoT, queryB, srcB, trgB, WsvA, WtvA };
  int pK[9]    = { 512, 2048, 2048, 1536, 512, 2048, 2048, 512, 512 };
  int ptype[9] = { 0, 0, 0, 0, 1, 1, 1, 1, 1 };
  int prows[9] = { 0, 0, 0, 0, 4096, 1152, 1152, 2048, 2048 };
  int pbase = 0;
  for (int i = 0; i < 9; ++i) {
    pj.src[i] = psrc[i]; pj.dst[i] = pdst[i]; pj.K[i] = pK[i]; pj.type[i] = ptype[i];
    pj.base[i] = pbase;
    pbase += ptype[i] ? (prows[i] / 64) * (pK[i] / 64) : (pK[i] / 64) * 8;
  }
  prep<<<pbase, 256, 0, stream>>>(pj);

  // 3. wprod: WsvPT = (Wsv@Wo2)^T, WtvPT = (Wtv@Wo3)^T  (mode-2 B-panel out)
  {
    GBatch wb;
    wb.swz = 1;
    GJob& a = wb.j[0];
    a.A0 = WoT + 512;                                  // Wo2^T rows
    a.Bt = WsvA; a.bias = nullptr; a.Cb = WsvPT; a.Cf = nullptr;
    a.Astride = 1536; a.Bstride = 512; a.Cstride = 2048;
    a.nTilesN = 16; a.nt = 8; a.mode = 2; a.tileBase = 0;
    GJob& b2 = wb.j[1];
    b2 = a;
    b2.A0 = WoT + 1024;
    b2.Bt = WtvA; b2.Cb = WtvPT;
    b2.tileBase = 128;
    for (int i = 2; i < 7; ++i) { wb.j[i] = b2; wb.j[i].tileBase = 0x7fffffff; }
    wb.njobs = 2;
    gemm_pipe<2, 4><<<256, 256, 0, stream>>>(wb);     // 256 blocks
  }

  // 4. merged projections (4,4)=128x128 tiles: s_key, t_key, svp, tvp, qh, P
  {
    GBatch pb;
    pb.swz = 0;
    int base = 0;
    // 4 big K=2048 jobs: 9 m-tiles x 4 n-tiles = 36 each
    const unsigned short* Aarr[4] = { srcB, trgB, srcB, trgB };
    const unsigned short* Barr[4] = { WsT, WtT, WsvPT, WtvPT };
    const float* biasArr[4] = { bs, bt, biasV, biasV + 512 };
    for (int i = 0; i < 4; ++i) {
      GJob& j = pb.j[i];
      j.A0 = Aarr[i];
      j.Bt = Barr[i]; j.bias = biasArr[i];
      if (i < 2) { j.Cb = (i ? t_key : s_key); j.Cf = nullptr; j.mode = 0; }
      else       { j.Cb = nullptr; j.Cf = (i == 2 ? svp : tvp); j.mode = 1; }
      j.Astride = 2048; j.Bstride = 2048; j.Cstride = 512;
      j.nTilesN = 4; j.nt = 32;
      j.tileBase = base; base += 9 * 4;
    }
    {                                          // qh = query@Wq + bq: 32x4 tiles
      GJob& j = pb.j[4];
      j.A0 = queryB;
      j.Bt = WqT; j.bias = bq; j.Cb = qh; j.Cf = nullptr;
      j.Astride = 512; j.Bstride = 512; j.Cstride = 512;
      j.nTilesN = 4; j.nt = 8; j.mode = 0;
      j.tileBase = base; base += 32 * 4;
    }
    {                                          // P = query@Wo1 + bo: 32x4 tiles
      GJob& j = pb.j[5];
      j.A0 = queryB;
      j.Bt = WoT; j.bias = bo; j.Cb = nullptr; j.Cf = P;
      j.Astride = 512; j.Bstride = 1536; j.Cstride = 512;
      j.nTilesN = 4; j.nt = 8; j.mode = 1;
      j.tileBase = base; base += 32 * 4;
    }
    pb.j[6] = pb.j[5]; pb.j[6].tileBase = 0x7fffffff;
    pb.njobs = 6;
    gemm_pipe<4, 4><<<base, 256, 0, stream>>>(pb);   // 400 blocks
  }

  // 5. fused scores + softmax + ctx + epilogue -> out (128 blocks)
  attn_fused<<<dim3(32, 4), 256, 0, stream>>>(qh, s_key, t_key, svp, tvp, P, out);
}

// Round 11
// 74.191 us; speedup vs baseline: 1.7060x; 1.3339x over previous
//
#include <hip/hip_runtime.h>
#include <hip/hip_bf16.h>
#include <math.h>

#define DEVI __device__ __forceinline__

typedef __attribute__((ext_vector_type(4))) float f32x4;
typedef __attribute__((ext_vector_type(8))) short bf16x8;

DEVI unsigned short f2bf(float f) {
  union { float f; unsigned int u; } v; v.f = f;
  return (unsigned short)((v.u + 0x7FFFu + ((v.u >> 16) & 1u)) >> 16);
}
DEVI float bf2f(unsigned short s) {
  union { unsigned int u; float f; } v; v.u = ((unsigned int)s) << 16; return v.f;
}
DEVI bf16x8 pack8(f32x4 a, f32x4 b) {
  bf16x8 r;
  r[0] = (short)f2bf(a[0]); r[1] = (short)f2bf(a[1]);
  r[2] = (short)f2bf(a[2]); r[3] = (short)f2bf(a[3]);
  r[4] = (short)f2bf(b[0]); r[5] = (short)f2bf(b[1]);
  r[6] = (short)f2bf(b[2]); r[7] = (short)f2bf(b[3]);
  return r;
}
DEVI void gload16(const unsigned short* g, unsigned short* l) {
  __builtin_amdgcn_global_load_lds(
      (const __attribute__((address_space(1))) unsigned int*)g,
      (__attribute__((address_space(3))) unsigned int*)l, 16, 0, 0);
}
// raw workgroup barrier WITHOUT the implicit vmcnt(0) drain of __syncthreads
#define SBAR() do { asm volatile("" ::: "memory"); \
                    __builtin_amdgcn_s_barrier();  \
                    asm volatile("" ::: "memory"); } while (0)

// ==== prep: weights f32[K][512] -> bf16 [512][K] swz ; f32[M][K] -> bf16 [M][K] swz
// swizzle: within each 64-elem k-group, kblock kb of row n stored at ((kb+n)&7).
struct PrepJobs {
  const float* src[9];
  unsigned short* dst[9];
  int K[9];
  int base[9];
  int type[9];   // 0 = weight transpose (64x64 tiles), 1 = row-major convert
};

__global__ __launch_bounds__(256) void prep(PrepJobs J) {
  __shared__ float t[64][65];   // 16.6 KB
  int tile = blockIdx.x;
  int job = 0;
  while (job < 8 && tile >= J.base[job + 1]) ++job;
  int tl = tile - J.base[job];
  int K = J.K[job];
  if (J.type[job] == 0) {
    int tn = tl & 7, tk = tl >> 3;   // 512/64 = 8 n-tiles
    int x = threadIdx.x & 63, y = threadIdx.x >> 6;
    const float* s = J.src[job];
    int k0 = tk * 64, n0 = tn * 64;
#pragma unroll
    for (int yy = y; yy < 64; yy += 4)
      t[yy][x] = s[(size_t)(k0 + yy) * 512 + n0 + x];
    __syncthreads();
    unsigned short* d = J.dst[job];
    int kb = (x >> 3) & 7, ko = x & 7;   // k = k0 + x, k0 % 64 == 0
#pragma unroll
    for (int yy = y; yy < 64; yy += 4) {
      int n = n0 + yy;
      int kswz = k0 + (((kb + n) & 7) << 3) + ko;
      d[(size_t)n * K + kswz] = f2bf(t[x][yy]);
    }
  } else {
    int nk = K >> 6;
    int rt = tl / nk;
    int r0 = rt * 64, k0 = (tl - rt * nk) * 64;
    int r = threadIdx.x >> 2, kq = threadIdx.x & 3;
    int row = r0 + r;
    const float* s = J.src[job] + (size_t)row * K + k0 + kq * 16;
    f32x4 a0 = *(const f32x4*)s;
    f32x4 a1 = *(const f32x4*)(s + 4);
    f32x4 a2 = *(const f32x4*)(s + 8);
    f32x4 a3 = *(const f32x4*)(s + 12);
    unsigned short* d = J.dst[job] + (size_t)row * K + k0;
    int kb0 = kq * 2;
    *(bf16x8*)(d + ((kb0 + row) & 7) * 8) = pack8(a0, a1);
    *(bf16x8*)(d + ((kb0 + 1 + row) & 7) * 8) = pack8(a2, a3);
  }
}

// ==== MFMA GEMM, counted-vmcnt double-buffer, templated tile ===============
// BM = MI*32, BN = NI*32, BK = 64; 4 waves (2m x 2n), wave tile (MI*16)x(NI*16).
// C[M][N] = A @ B (+ bias). A/B bf16 pre-swizzled; staging is pure
// global_load_lds DMA; s_waitcnt vmcnt(MI+NI) keeps next tile in flight.
// mode 0: bf16 row-major out. mode 2: bf16 out with per-row k-group swizzle
// (so C can be consumed as an A/B operand by a later GEMM).
struct GJob {
  const unsigned short* A0;
  const unsigned short* Bt;
  const float* bias;        // may be nullptr
  unsigned short* Cb;
  int Astride, Bstride, Cstride, nTilesN, nt, mode, tileBase;
};
struct GBatch { GJob j[7]; int njobs; int swz; };

template <int MI, int NI>
__global__ __launch_bounds__(256) void gemm_pipe(GBatch batch) {
  constexpr int BM = MI * 32, BN = NI * 32;
  int gt = blockIdx.x;
  if (batch.swz) {                         // XCD swizzle only for homogeneous grids
    int cpx = gridDim.x >> 3;
    gt = (blockIdx.x & 7) * cpx + (blockIdx.x >> 3);
  }
  int job = 0;
#pragma unroll
  for (int i = 1; i < 7; ++i)
    if (i < batch.njobs && gt >= batch.j[i].tileBase) job = i;
  GJob J = batch.j[job];
  int tl = gt - J.tileBase;
  int bm = (tl / J.nTilesN) * BM, bn = (tl % J.nTilesN) * BN;

  __shared__ __align__(16) unsigned short La[2][BM * 64];
  __shared__ __align__(16) unsigned short Lb[2][BN * 64];

  int tid = threadIdx.x;
  int wave = tid >> 6, lane = tid & 63;
  int lrow = lane & 15, lq = lane >> 4;
  int wr = (wave >> 1) * (MI * 16), wc = (wave & 1) * (NI * 16);
  f32x4 acc[MI][NI] = {};

  int nt = J.nt;

  auto stage_both = [&](int t, int buf) {
    const unsigned short* GA = J.A0 + (size_t)bm * J.Astride + (size_t)(t << 6);
    const unsigned short* GB = J.Bt + (size_t)bn * J.Bstride + (size_t)(t << 6);
#pragma unroll
    for (int p = 0; p < MI; ++p) {     // A: BM*64 bf16 = MI*256 slots of 16B
      int s = p * 256 + tid;
      gload16(GA + (size_t)(s >> 3) * J.Astride + (s & 7) * 8,
              &La[buf][(size_t)(p * 256 + wave * 64) * 8]);
    }
#pragma unroll
    for (int p = 0; p < NI; ++p) {     // B: BN*64 bf16 = NI*256 slots
      int s = p * 256 + tid;
      gload16(GB + (size_t)(s >> 3) * J.Bstride + (s & 7) * 8,
              &Lb[buf][(size_t)(p * 256 + wave * 64) * 8]);
    }
  };

  stage_both(0, 0);
  if (nt > 1) stage_both(1, 1);

  for (int t = 0; t < nt; ++t) {
    // wait until THIS tile's DMA landed; next tile's (MI+NI) stay in flight
    if (t + 1 < nt) {
      if constexpr (MI + NI == 8)      asm volatile("s_waitcnt vmcnt(8)" ::: "memory");
      else if constexpr (MI + NI == 6) asm volatile("s_waitcnt vmcnt(6)" ::: "memory");
      else                             asm volatile("s_waitcnt vmcnt(4)" ::: "memory");
    } else {
      asm volatile("s_waitcnt vmcnt(0)" ::: "memory");
    }
    SBAR();                              // all waves' tile-t data visible
    int cur = t & 1;
#pragma unroll
    for (int kc = 0; kc < 2; ++kc) {
      int kb = kc * 4 + lq;
      bf16x8 af[MI], bv[NI];
#pragma unroll
      for (int mi = 0; mi < MI; ++mi) {
        int r = wr + mi * 16 + lrow;
        af[mi] = *(const bf16x8*)&La[cur][r * 64 + ((kb + r) & 7) * 8];
      }
#pragma unroll
      for (int ni = 0; ni < NI; ++ni) {
        int r = wc + ni * 16 + lrow;
        bv[ni] = *(const bf16x8*)&Lb[cur][r * 64 + ((kb + r) & 7) * 8];
      }
#pragma unroll
      for (int mi = 0; mi < MI; ++mi)
#pragma unroll
        for (int ni = 0; ni < NI; ++ni)
          acc[mi][ni] = __builtin_amdgcn_mfma_f32_16x16x32_bf16(af[mi], bv[ni], acc[mi][ni], 0, 0, 0);
    }
    SBAR();                              // all waves done reading buf[cur]
    if (t + 2 < nt) stage_both(t + 2, cur);   // refill freed buffer
  }

  // epilogue: C/D layout col=lane&15, row=lq*4+reg
#pragma unroll
  for (int mi = 0; mi < MI; ++mi) {
#pragma unroll
    for (int ni = 0; ni < NI; ++ni) {
      int gn = bn + wc + ni * 16 + lrow;
      float bvs = J.bias ? J.bias[gn] : 0.f;
      int gm0 = bm + wr + mi * 16 + lq * 4;
      if (J.mode == 0) {
#pragma unroll
        for (int r = 0; r < 4; ++r)
          J.Cb[(size_t)(gm0 + r) * J.Cstride + gn] = f2bf(acc[mi][ni][r] + bvs);
      } else {
        // mode 2: store so row-major [M][N] reads as a swizzled GEMM operand
#pragma unroll
        for (int r = 0; r < 4; ++r) {
          int row = gm0 + r;
          int col = (gn & ~63) | (((((gn >> 3) & 7) + row) & 7) << 3) | (gn & 7);
          J.Cb[(size_t)row * J.Cstride + col] = f2bf(acc[mi][ni][r] + bvs);
        }
      }
    }
  }
}

// ==== fused scores + separable softmax + ctx + output ======================
// ws[l,i] = softmax_i(cc q.t_key[i]);  wt[l,j] = softmax_j(cc q.s_key[j])
// out[l,h] = relu(P[l,h] + sum_i ws[l,i] svp[i,h] + sum_j wt[l,j] tvp[j,h])
// Grid (32 b, 8 lc): 16 l-rows per block. 4 waves: (mat, k-half) k-split with
// LDS reduce -> all waves busy; 256 blocks = 2x the old occupancy.
__global__ __launch_bounds__(256) void attn_fused(
    const unsigned short* __restrict__ qh, const unsigned short* __restrict__ s_key,
    const unsigned short* __restrict__ t_key, const unsigned short* __restrict__ svp,
    const unsigned short* __restrict__ tvp, const unsigned short* __restrict__ Pb,
    float* __restrict__ out) {
  __shared__ float red[4][3][64][4];   // 12 KB: [wave][nf][lane][r]
  __shared__ float wlT[2][36][16];     // 4.6 KB: [mat][j][l]
  int b = blockIdx.x, lc = blockIdx.y;
  int tid = threadIdx.x, wave = tid >> 6, lane = tid & 63;
  int lrow = lane & 15, lq = lane >> 4;
  int mat = wave >> 1, kh = wave & 1;
  int row0 = b * 128 + lc * 16;
  const unsigned short* qp = qh + (size_t)row0 * 512;
  const unsigned short* key = (mat ? s_key : t_key) + (size_t)b * 36 * 512;
  f32x4 acc[3] = {};
  for (int kc = kh * 8; kc < kh * 8 + 8; ++kc) {
    int k = kc * 32 + lq * 8;
    bf16x8 af = *(const bf16x8*)(qp + (size_t)lrow * 512 + k);
#pragma unroll
    for (int nf = 0; nf < 3; ++nf) {
      int n = nf * 16 + lrow; if (n > 35) n = 35;   // clamp; masked in softmax
      bf16x8 bv = *(const bf16x8*)(key + (size_t)n * 512 + k);
      acc[nf] = __builtin_amdgcn_mfma_f32_16x16x32_bf16(af, bv, acc[nf], 0, 0, 0);
    }
  }
#pragma unroll
  for (int nf = 0; nf < 3; ++nf)
    *(f32x4*)&red[wave][nf][lane][0] = acc[nf];
  __syncthreads();

  if (kh == 0) {       // waves 0 (mat=t->ws) and 2 (mat=s->wt) do the softmax
    const float ccs = 0.022097086912079608f;   // 0.5 / sqrt(512)
    float ex[3][4];
#pragma unroll
    for (int r = 0; r < 4; ++r) {
      float a0 = (red[wave][0][lane][r] + red[wave + 1][0][lane][r]) * ccs;
      float a1 = (red[wave][1][lane][r] + red[wave + 1][1][lane][r]) * ccs;
      float a2 = (lrow < 4)
          ? (red[wave][2][lane][r] + red[wave + 1][2][lane][r]) * ccs : -1e30f;
      float mx = fmaxf(fmaxf(a0, a1), a2);
      for (int s = 1; s < 16; s <<= 1) mx = fmaxf(mx, __shfl_xor(mx, s));
      float e0 = __expf(a0 - mx), e1 = __expf(a1 - mx);
      float e2 = (lrow < 4) ? __expf(a2 - mx) : 0.f;
      float sum = e0 + e1 + e2;
      for (int s = 1; s < 16; s <<= 1) sum += __shfl_xor(sum, s);
      float inv = 1.f / sum;
      ex[0][r] = e0 * inv; ex[1][r] = e1 * inv; ex[2][r] = e2 * inv;
    }
#pragma unroll
    for (int nf = 0; nf < 3; ++nf) {
      int col = nf * 16 + lrow;
      if (col < 36) {
#pragma unroll
        for (int r = 0; r < 4; ++r)
          wlT[mat][col][lq * 4 + r] = ex[nf][r];
      }
    }
  }
  __syncthreads();

  // ctx phase: thread (lgrp, hgrp) handles 4 l-rows x 8 h, both mats summed
  int lgrp = tid >> 6, hgrp = tid & 63;
  float a2[4][8] = {};
#pragma unroll
  for (int m = 0; m < 2; ++m) {
    const unsigned short* V = (m ? tvp : svp) + (size_t)b * 36 * 512;
    for (int j = 0; j < 36; ++j) {
      f32x4 wa = *(const f32x4*)&wlT[m][j][lgrp * 4];       // broadcast
      bf16x8 v = *(const bf16x8*)(V + (size_t)j * 512 + hgrp * 8);
      float vf[8];
#pragma unroll
      for (int hi = 0; hi < 8; ++hi) vf[hi] = bf2f((unsigned short)v[hi]);
#pragma unroll
      for (int li = 0; li < 4; ++li)
#pragma unroll
        for (int hi = 0; hi < 8; ++hi) a2[li][hi] += wa[li] * vf[hi];
    }
  }
#pragma unroll
  for (int li = 0; li < 4; ++li) {
    int R = row0 + lgrp * 4 + li;
    bf16x8 p = *(const bf16x8*)(Pb + (size_t)R * 512 + hgrp * 8);
    float* op = out + (size_t)R * 512 + hgrp * 8;
    f32x4 o0, o1;
#pragma unroll
    for (int hi = 0; hi < 4; ++hi) {
      o0[hi] = fmaxf(bf2f((unsigned short)p[hi]) + a2[li][hi], 0.f);
      o1[hi] = fmaxf(bf2f((unsigned short)p[4 + hi]) + a2[li][4 + hi], 0.f);
    }
    *(f32x4*)op = o0;
    *(f32x4*)(op + 4) = o1;
  }
}

// ---------------------------------------------------------------------------
extern "C" void kernel_launch(void* const* d_in, const int* in_sizes, int n_in,
                              void* d_out, int out_size, void* d_ws, size_t ws_size,
                              hipStream_t stream) {
  (void)in_sizes; (void)n_in; (void)out_size; (void)ws_size;
  const float* query = (const float*)d_in[0];
  const float* src   = (const float*)d_in[1];
  const float* trg   = (const float*)d_in[2];
  const float* Wq  = (const float*)d_in[3];  const float* bq  = (const float*)d_in[4];
  const float* Wsk = (const float*)d_in[5];  const float* bs  = (const float*)d_in[6];
  const float* Wtk = (const float*)d_in[7];  const float* bt  = (const float*)d_in[8];
  const float* Wsv = (const float*)d_in[9];  const float* bsv = (const float*)d_in[10];
  const float* Wtv = (const float*)d_in[11]; const float* btv = (const float*)d_in[12];
  const float* Wo  = (const float*)d_in[13]; const float* bo  = (const float*)d_in[14];

  // workspace (bf16 shorts) ~38 MB
  unsigned short* WqT    = (unsigned short*)d_ws;     // 512*512
  unsigned short* WsT    = WqT  + 512 * 512;          // 512*2048
  unsigned short* WtT    = WsT  + 512 * 2048;
  unsigned short* WsvT   = WtT  + 512 * 2048;
  unsigned short* WtvT   = WsvT + 512 * 2048;
  unsigned short* WoT    = WtvT + 512 * 2048;         // 512*1536
  unsigned short* queryB = WoT  + 512 * 1536;         // 4096*512 swz
  unsigned short* srcB   = queryB + 4096 * 512;       // 1152*2048 swz
  unsigned short* trgB   = srcB + 1152 * 2048;
  unsigned short* qh     = trgB + 1152 * 2048;        // 4096*512 plain
  unsigned short* s_key  = qh + 4096 * 512;           // 1152*512 plain
  unsigned short* t_key  = s_key + 1152 * 512;
  unsigned short* s_val  = t_key + 1152 * 512;        // 1152*512 A-swz (mode 2)
  unsigned short* t_val  = s_val + 1152 * 512;
  unsigned short* svp    = t_val + 1152 * 512;        // 1152*512 plain
  unsigned short* tvp    = svp + 1152 * 512;
  unsigned short* Pb     = tvp + 1152 * 512;          // 4096*512 plain
  float* out = (float*)d_out;

  // 1. prep: 6 weight transposes + 3 activation converts
  PrepJobs pj;
  const float* psrc[9] = { Wq, Wsk, Wtk, Wsv, Wtv, Wo, query, src, trg };
  unsigned short* pdst[9] = { WqT, WsT, WtT, WsvT, WtvT, WoT, queryB, srcB, trgB };
  int pK[9]    = { 512, 2048, 2048, 2048, 2048, 1536, 512, 2048, 2048 };
  int ptype[9] = { 0, 0, 0, 0, 0, 0, 1, 1, 1 };
  int prows[9] = { 0, 0, 0, 0, 0, 0, 4096, 1152, 1152 };
  int pbase = 0;
  for (int i = 0; i < 9; ++i) {
    pj.src[i] = psrc[i]; pj.dst[i] = pdst[i]; pj.K[i] = pK[i]; pj.type[i] = ptype[i];
    pj.base[i] = pbase;
    pbase += ptype[i] ? (prows[i] / 64) * (pK[i] / 64) : (pK[i] / 64) * 8;
  }
  prep<<<pbase, 256, 0, stream>>>(pj);

  // 2. merged projections (2,4)=64x128 tiles, 800 blocks:
  //    s_key, t_key (mode 0) | s_val, t_val (mode 2, A-format) | qh, Pb (mode 0)
  {
    GBatch pb;
    pb.swz = 0;                 // natural round-robin balances long/short blocks
    int base = 0;
    const unsigned short* Aarr[4] = { srcB, trgB, srcB, trgB };
    const unsigned short* Barr[4] = { WsT, WtT, WsvT, WtvT };
    const float* biasArr[4] = { bs, bt, bsv, btv };
    unsigned short* Carr[4] = { s_key, t_key, s_val, t_val };
    for (int i = 0; i < 4; ++i) {     // 4 big K=2048 jobs: 18 m x 4 n = 72 tiles
      GJob& j = pb.j[i];
      j.A0 = Aarr[i]; j.Bt = Barr[i]; j.bias = biasArr[i]; j.Cb = Carr[i];
      j.Astride = 2048; j.Bstride = 2048; j.Cstride = 512;
      j.nTilesN = 4; j.nt = 32; j.mode = (i < 2) ? 0 : 2;
      j.tileBase = base; base += 18 * 4;
    }
    {                                  // qh = query@Wq + bq: 64x4 = 256 tiles
      GJob& j = pb.j[4];
      j.A0 = queryB; j.Bt = WqT; j.bias = bq; j.Cb = qh;
      j.Astride = 512; j.Bstride = 512; j.Cstride = 512;
      j.nTilesN = 4; j.nt = 8; j.mode = 0;
      j.tileBase = base; base += 64 * 4;
    }
    {                                  // Pb = query@Wo1 + bo: 256 tiles
      GJob& j = pb.j[5];
      j.A0 = queryB; j.Bt = WoT; j.bias = bo; j.Cb = Pb;
      j.Astride = 512; j.Bstride = 1536; j.Cstride = 512;
      j.nTilesN = 4; j.nt = 8; j.mode = 0;
      j.tileBase = base; base += 64 * 4;
    }
    pb.j[6] = pb.j[5]; pb.j[6].tileBase = 0x7fffffff;
    pb.njobs = 6;
    gemm_pipe<2, 4><<<base, 256, 0, stream>>>(pb);   // 800 blocks
  }

  // 3. svgemm (2,2)=64x64 tiles: svp = s_val@Wo2, tvp = t_val@Wo3  (288 blocks)
  {
    GBatch sb;
    sb.swz = 1;                 // homogeneous, 288 % 8 == 0
    GJob& a = sb.j[0];
    a.A0 = s_val; a.Bt = WoT + 512; a.bias = nullptr; a.Cb = svp;
    a.Astride = 512; a.Bstride = 1536; a.Cstride = 512;
    a.nTilesN = 8; a.nt = 8; a.mode = 0; a.tileBase = 0;
    GJob& b2 = sb.j[1];
    b2 = a;
    b2.A0 = t_val; b2.Bt = WoT + 1024; b2.Cb = tvp;
    b2.tileBase = 18 * 8;       // 144
    for (int i = 2; i < 7; ++i) { sb.j[i] = b2; sb.j[i].tileBase = 0x7fffffff; }
    sb.njobs = 2;
    gemm_pipe<2, 2><<<288, 256, 0, stream>>>(sb);
  }

  // 4. fused scores + softmax + ctx + epilogue -> out (256 blocks)
  attn_fused<<<dim3(32, 8), 256, 0, stream>>>(qh, s_key, t_key, svp, tvp, Pb, out);
}